// Round 5
// baseline (929.497 us; speedup 1.0000x reference)
//
#include <hip/hip_runtime.h>
#include <cstdio>
#include <cstdint>

#define TOKENS 8192
#define DMODEL 1024
#define DFF    4096
#define NEXP   8
#define TCAP   8192    // per-expert list capacity (each token picks 2 distinct experts)
#define ROWS   16384   // total token-expert rows

typedef __attribute__((ext_vector_type(8))) short short8;
typedef __attribute__((ext_vector_type(4))) float f32x4;

__device__ __forceinline__ unsigned short f2bf(float f){
  unsigned u = __builtin_bit_cast(unsigned, f);
  u += 0x7FFFu + ((u >> 16) & 1u);          // RNE
  return (unsigned short)(u >> 16);
}

__device__ __forceinline__ void async16(void* lds, const void* g){
  __builtin_amdgcn_global_load_lds((const __attribute__((address_space(1))) void*)g,
                                   (__attribute__((address_space(3))) void*)lds,
                                   16, 0, 0);
}

__device__ __forceinline__ float gelu_tanh(float x){
  // jax.nn.gelu default: approximate=True (tanh form)
  float t = 0.7978845608028654f * (x + 0.044715f * x * x * x);
  float e = __expf(2.0f * t);
  float th = 1.0f - 2.0f / (e + 1.0f);      // safe at e=inf -> th=1
  return 0.5f * x * (1.0f + th);
}

// ---------------- router: logits, top-2, softmax, list build ----------------
__global__ __launch_bounds__(256) void router_kernel(
    const float* __restrict__ x, const float* __restrict__ Wr, const float* __restrict__ br,
    int* __restrict__ cnt, int* __restrict__ list,
    int* __restrict__ tk_e, int* __restrict__ tk_s, float* __restrict__ tk_g)
{
  int t = blockIdx.x * 4 + (threadIdx.x >> 6);
  int lane = threadIdx.x & 63;
  const float* xr = x + (size_t)t * DMODEL;
  float acc[8];
#pragma unroll
  for (int e = 0; e < 8; e++) acc[e] = 0.f;
#pragma unroll
  for (int j = 0; j < 16; j++){
    int d = lane + 64 * j;
    float xv = xr[d];
    const f32x4* w = (const f32x4*)(Wr + (size_t)d * 8);
    f32x4 w0 = w[0], w1 = w[1];
    acc[0] += xv * w0.x; acc[1] += xv * w0.y; acc[2] += xv * w0.z; acc[3] += xv * w0.w;
    acc[4] += xv * w1.x; acc[5] += xv * w1.y; acc[6] += xv * w1.z; acc[7] += xv * w1.w;
  }
#pragma unroll
  for (int e = 0; e < 8; e++){
    float v = acc[e];
#pragma unroll
    for (int o = 32; o > 0; o >>= 1) v += __shfl_xor(v, o, 64);
    acc[e] = v;
  }
  if (lane == 0){
    float lg[8];
#pragma unroll
    for (int e = 0; e < 8; e++) lg[e] = acc[e] + br[e];
    int i0 = 0; float v0 = lg[0];
#pragma unroll
    for (int e = 1; e < 8; e++) if (lg[e] > v0){ v0 = lg[e]; i0 = e; }   // first max (tie: lowest idx)
    int i1 = -1; float v1 = -3.4e38f;
#pragma unroll
    for (int e = 0; e < 8; e++) if (e != i0 && lg[e] > v1){ v1 = lg[e]; i1 = e; }
    float ew = __expf(v1 - v0);               // <= 1
    float w1 = ew / (1.f + ew);
    float w0 = 1.f - w1;
    int s0 = atomicAdd(&cnt[i0], 1);
    int s1 = atomicAdd(&cnt[i1], 1);
    list[i0 * TCAP + s0] = t;
    list[i1 * TCAP + s1] = t;
    tk_e[2*t]   = i0; tk_s[2*t]   = s0; tk_g[2*t]   = w0;
    tk_e[2*t+1] = i1; tk_s[2*t+1] = s1; tk_g[2*t+1] = w1;
  }
}

__global__ void scan_kernel(const int* __restrict__ cnt, int* __restrict__ off){
  if (threadIdx.x == 0 && blockIdx.x == 0){
    int o = 0;
    for (int e = 0; e < NEXP; e++){ off[e] = o; o += cnt[e]; }
    off[NEXP] = o;
  }
}

// ---------------- x fp32 -> bf16 ----------------
__global__ __launch_bounds__(256) void xconv_kernel(const float* __restrict__ x,
                                                    unsigned short* __restrict__ xb)
{
  size_t i = (size_t)(blockIdx.x * 256 + threadIdx.x) * 8;
  f32x4 a = *(const f32x4*)(x + i);
  f32x4 b = *(const f32x4*)(x + i + 4);
  short8 o;
  o[0]=(short)f2bf(a.x); o[1]=(short)f2bf(a.y); o[2]=(short)f2bf(a.z); o[3]=(short)f2bf(a.w);
  o[4]=(short)f2bf(b.x); o[5]=(short)f2bf(b.y); o[6]=(short)f2bf(b.z); o[7]=(short)f2bf(b.w);
  *(short8*)(xb + i) = o;
}

// ---------------- weight transpose + fp32->bf16:  src[E][R][C] -> dst[E][C][R] ----------------
__global__ __launch_bounds__(256) void transpose_kernel(const float* __restrict__ src,
                                                        unsigned short* __restrict__ dst,
                                                        int R, int C)
{
  __shared__ float tile[32][33];
  int e = blockIdx.z;
  size_t ebase = (size_t)e * R * C;
  int c0 = blockIdx.x * 32;
  int r0 = blockIdx.y * 32;
  int tx = threadIdx.x & 31;
  int ty = threadIdx.x >> 5;      // 0..7
  const float* s = src + ebase;
  unsigned short* d = dst + ebase;
#pragma unroll
  for (int i = 0; i < 4; i++)
    tile[ty + 8*i][tx] = s[(size_t)(r0 + ty + 8*i) * C + c0 + tx];
  __syncthreads();
#pragma unroll
  for (int i = 0; i < 4; i++)
    d[(size_t)(c0 + ty + 8*i) * R + r0 + tx] = f2bf(tile[tx][ty + 8*i]);
}

// ---------------- grouped GEMM (B pre-transposed bf16) ----------------
// 256x128 tile, BK=64, 512 threads (8 waves as 4Mx2N, per-wave 64x64 output).
// 3-buffer LDS pipeline, prefetch distance 2, counted s_waitcnt vmcnt(6) (T4),
// ONE barrier per k-step. Loads get ~2 k-steps to land (covers ~900cyc HBM lat).
// MODE 0: h = gelu(A@B^T + b1) -> bf16 ;  MODE 1: y (+)= A@B^T -> fp32
template<int MODE>
__global__ __launch_bounds__(512, 1) void gemm_kernel(
    const unsigned short* __restrict__ A0, int lda,
    const int* __restrict__ list,                    // null => rows are off[e]+r
    const unsigned short* __restrict__ B0, int ldb, long strideBe,
    const int* __restrict__ cnt, const int* __restrict__ off,
    int K,
    unsigned short* __restrict__ hout, float* __restrict__ yout, int ldout,
    const float* __restrict__ bias, int nbase, int accum)
{
  int e = blockIdx.z;
  int cnte = cnt[e];
  int bm = blockIdx.y;
  if (bm * 256 >= cnte) return;
  int bn = blockIdx.x;
  int offe = off[e];

  // 3 buffers x (A 32KB + B 16KB) = 144KB
  __shared__ unsigned short smem[3][(256 + 128) * 64];

  int tid  = threadIdx.x;
  int lane = tid & 63;
  int wav  = tid >> 6;        // 0..7
  int slot = tid & 7;

  // staging source pointers: A = 4 x async16/thread, B = 2 x async16/thread per k-step
  const unsigned short* aptr[4];
  const unsigned short* bptr[2];
  const unsigned short* Be = B0 + (size_t)e * strideBe;
#pragma unroll
  for (int c = 0; c < 4; c++){
    int r  = bm * 256 + c * 64 + (tid >> 3);        // global tile row
    int rr = min(r, cnte - 1);
    long arow = list ? (long)list[(size_t)e * TCAP + rr] : (long)(offe + rr);
    aptr[c] = A0 + (size_t)arow * lda + slot * 8;
  }
#pragma unroll
  for (int c = 0; c < 2; c++){
    int n = bn * 128 + c * 64 + (tid >> 3);
    bptr[c] = Be + (size_t)n * ldb + slot * 8;
  }

  auto stage = [&](int buf, int k0){
    char* Ad = (char*)smem + (size_t)buf * 49152;
    char* Bd = Ad + 32768;
#pragma unroll
    for (int c = 0; c < 4; c++)
      async16(Ad + c * 8192 + wav * 1024, aptr[c] + k0);
#pragma unroll
    for (int c = 0; c < 2; c++)
      async16(Bd + c * 8192 + wav * 1024, bptr[c] + k0);
  };

  f32x4 acc[4][4] = {};

  int wm = wav >> 1, wn = wav & 1;
  int l15 = lane & 15, l4 = lane >> 4;

  int NT = K >> 6;
  stage(0, 0);
  stage(1, 64);
  int cur = 0;
  for (int t = 0; t < NT; t++){
    // tile t landed (mine): oldest 6 of <=12 outstanding
    if (t < NT - 1) asm volatile("s_waitcnt vmcnt(6)" ::: "memory");
    else            asm volatile("s_waitcnt vmcnt(0)" ::: "memory");
    __builtin_amdgcn_s_barrier();                    // all waves: tile t landed; step t-1 reads done
    if (t + 2 < NT) stage((cur + 2) % 3, (t + 2) << 6);   // overwrites buf read at t-1: safe
    char* Ab = (char*)smem + (size_t)cur * 49152;
    char* Bb = Ab + 32768;
#pragma unroll
    for (int kk = 0; kk < 2; kk++){
      short8 a[4], b[4];
      int k8 = kk * 4 + l4;
#pragma unroll
      for (int m = 0; m < 4; m++){
        int row = wm * 64 + m * 16 + l15;
        a[m] = *(const short8*)(Ab + row * 128 + (k8 << 4));
      }
#pragma unroll
      for (int n = 0; n < 4; n++){
        int col = wn * 64 + n * 16 + l15;
        b[n] = *(const short8*)(Bb + col * 128 + (k8 << 4));
      }
#pragma unroll
      for (int m = 0; m < 4; m++)
#pragma unroll
        for (int n = 0; n < 4; n++)
          acc[m][n] = __builtin_amdgcn_mfma_f32_16x16x32_bf16(a[m], b[n], acc[m][n], 0, 0, 0);
    }
    cur = (cur + 1) % 3;
  }

  // epilogue: C/D layout col=lane&15, row=(lane>>4)*4+q  [verified m89/m91]
#pragma unroll
  for (int m = 0; m < 4; m++){
#pragma unroll
    for (int n = 0; n < 4; n++){
      int coll = bn * 128 + wn * 64 + n * 16 + l15;
#pragma unroll
      for (int q = 0; q < 4; q++){
        int r = bm * 256 + wm * 64 + m * 16 + l4 * 4 + q;
        if (r < cnte){
          float v = acc[m][n][q];
          size_t orow = (size_t)(offe + r);
          if (MODE == 0){
            v += bias[(size_t)e * DFF + nbase + coll];
            v = gelu_tanh(v);
            hout[orow * (size_t)ldout + coll] = f2bf(v);
          } else {
            size_t oi = orow * (size_t)ldout + coll;
            if (accum) v += yout[oi];
            yout[oi] = v;
          }
        }
      }
    }
  }
}

// ---------------- combine: out[t] = sum_k g_k * (y[row_k] + b2[e_k]) ----------------
__global__ __launch_bounds__(256) void combine_kernel(
    const float* __restrict__ y, const float* __restrict__ b2,
    const int* __restrict__ off, const int* __restrict__ tk_e,
    const int* __restrict__ tk_s, const float* __restrict__ tk_g,
    float* __restrict__ out)
{
  int t = blockIdx.x;
  int d = threadIdx.x * 4;
  int e0 = tk_e[2*t],  e1 = tk_e[2*t+1];
  int s0 = tk_s[2*t],  s1 = tk_s[2*t+1];
  float g0 = tk_g[2*t], g1 = tk_g[2*t+1];
  size_t r0 = (size_t)(off[e0] + s0) * DMODEL + d;
  size_t r1 = (size_t)(off[e1] + s1) * DMODEL + d;
  f32x4 v0 = *(const f32x4*)(y + r0);
  f32x4 v1 = *(const f32x4*)(y + r1);
  f32x4 c0 = *(const f32x4*)(b2 + (size_t)e0 * DMODEL + d);
  f32x4 c1 = *(const f32x4*)(b2 + (size_t)e1 * DMODEL + d);
  f32x4 o  = g0 * (v0 + c0) + g1 * (v1 + c1);
  *(f32x4*)(out + (size_t)t * DMODEL + d) = o;
}

extern "C" void kernel_launch(void* const* d_in, const int* in_sizes, int n_in,
                              void* d_out, int out_size, void* d_ws, size_t ws_size,
                              hipStream_t stream)
{
  const float* x  = (const float*)d_in[0];
  const float* Wr = (const float*)d_in[1];
  const float* br = (const float*)d_in[2];
  const float* W1 = (const float*)d_in[3];
  const float* b1 = (const float*)d_in[4];
  const float* W2 = (const float*)d_in[5];
  const float* b2 = (const float*)d_in[6];
  float* out = (float*)d_out;

  char* ws = (char*)d_ws;
  size_t o = 0;
  auto carve = [&](size_t bytes) -> char* {
    char* p = ws + o;
    o += (bytes + 255) & ~(size_t)255;
    return p;
  };
  int* cnt   = (int*)carve(NEXP * 4);
  int* off   = (int*)carve((NEXP + 1) * 4);
  int* list  = (int*)carve((size_t)NEXP * TCAP * 4);
  int* tk_e  = (int*)carve(TOKENS * 2 * 4);
  int* tk_s  = (int*)carve(TOKENS * 2 * 4);
  float* tk_g = (float*)carve(TOKENS * 2 * 4);
  unsigned short* xb  = (unsigned short*)carve((size_t)TOKENS * DMODEL * 2);
  unsigned short* W1t = (unsigned short*)carve((size_t)NEXP * DFF * DMODEL * 2);
  unsigned short* W2t = (unsigned short*)carve((size_t)NEXP * DFF * DMODEL * 2);
  float* y = (float*)carve((size_t)ROWS * DMODEL * 4);
  size_t used_base = o;

  int nchunk = 0;
  for (int nc = 1; nc <= 8; nc <<= 1){
    size_t need = used_base + (size_t)ROWS * (DFF / nc) * 2 + 256;
    if (need <= ws_size){ nchunk = nc; break; }
  }
  if (!nchunk){
    fprintf(stderr, "kernel_launch: ws too small (%zu bytes, need >= %zu)\n",
            ws_size, used_base + (size_t)ROWS * (DFF / 8) * 2 + 256);
    return;
  }
  int dffc = DFF / nchunk;
  unsigned short* h = (unsigned short*)carve((size_t)ROWS * dffc * 2);

  hipMemsetAsync(cnt, 0, NEXP * 4, stream);
  router_kernel<<<TOKENS / 4, 256, 0, stream>>>(x, Wr, br, cnt, list, tk_e, tk_s, tk_g);
  scan_kernel<<<1, 64, 0, stream>>>(cnt, off);
  xconv_kernel<<<(TOKENS * DMODEL / 8) / 256, 256, 0, stream>>>(x, xb);
  // W1 [E][D][DFF] -> W1t [E][DFF][D]
  transpose_kernel<<<dim3(DFF / 32, DMODEL / 32, NEXP), 256, 0, stream>>>(W1, W1t, DMODEL, DFF);
  // W2 [E][DFF][D] -> W2t [E][D][DFF]
  transpose_kernel<<<dim3(DMODEL / 32, DFF / 32, NEXP), 256, 0, stream>>>(W2, W2t, DFF, DMODEL);

  for (int c = 0; c < nchunk; c++){
    // GEMM1: h[:, 0:dffc] = gelu(x[list] @ W1t(slice)^T + b1(slice))
    gemm_kernel<0><<<dim3(dffc / 128, 16, NEXP), 512, 0, stream>>>(
        xb, DMODEL, list,
        W1t + (size_t)c * dffc * DMODEL, DMODEL, (long)DFF * DMODEL,
        cnt, off, DMODEL,
        h, nullptr, dffc,
        b1, c * dffc, 0);
    // GEMM2: y (+)= h @ W2t(slice)^T
    gemm_kernel<1><<<dim3(DMODEL / 128, 16, NEXP), 512, 0, stream>>>(
        h, dffc, nullptr,
        W2t + (size_t)c * dffc, DFF, (long)DFF * DMODEL,
        cnt, off, dffc,
        nullptr, y, DMODEL,
        nullptr, 0, c > 0);
  }
  combine_kernel<<<TOKENS, 256, 0, stream>>>(y, b2, off, tk_e, tk_s, tk_g, out);
}

// Round 6
// 800.971 us; speedup vs baseline: 1.1605x; 1.1605x over previous
//
#include <hip/hip_runtime.h>
#include <cstdio>
#include <cstdint>

#define TOKENS 8192
#define DMODEL 1024
#define DFF    4096
#define NEXP   8
#define TCAP   8192    // per-expert list capacity (each token picks 2 distinct experts)
#define ROWS   16384   // total token-expert rows

typedef __attribute__((ext_vector_type(8))) short short8;
typedef __attribute__((ext_vector_type(4))) float f32x4;

__device__ __forceinline__ unsigned short f2bf(float f){
  unsigned u = __builtin_bit_cast(unsigned, f);
  u += 0x7FFFu + ((u >> 16) & 1u);          // RNE
  return (unsigned short)(u >> 16);
}

__device__ __forceinline__ void async16(void* lds, const void* g){
  __builtin_amdgcn_global_load_lds((const __attribute__((address_space(1))) void*)g,
                                   (__attribute__((address_space(3))) void*)lds,
                                   16, 0, 0);
}

// Opaque LDS read: compiler cannot see this touches LDS, so it will NOT insert
// a conservative s_waitcnt vmcnt(0) against in-flight global_load_lds (the
// round-5 serializer). We order it ourselves: asm lgkmcnt(0) + sched_barrier(0)
// before the consuming MFMAs (rule #18).
__device__ __forceinline__ short8 lds_read_b128(const char* p){
  short8 r;
  asm volatile("ds_read_b128 %0, %1"
               : "=v"(r)
               : "v"((const __attribute__((address_space(3))) char*)p));
  return r;
}

__device__ __forceinline__ float gelu_tanh(float x){
  // jax.nn.gelu default: approximate=True (tanh form)
  float t = 0.7978845608028654f * (x + 0.044715f * x * x * x);
  float e = __expf(2.0f * t);
  float th = 1.0f - 2.0f / (e + 1.0f);      // safe at e=inf -> th=1
  return 0.5f * x * (1.0f + th);
}

// ---------------- router: logits, top-2, softmax, list build ----------------
__global__ __launch_bounds__(256) void router_kernel(
    const float* __restrict__ x, const float* __restrict__ Wr, const float* __restrict__ br,
    int* __restrict__ cnt, int* __restrict__ list,
    int* __restrict__ tk_e, int* __restrict__ tk_s, float* __restrict__ tk_g)
{
  int t = blockIdx.x * 4 + (threadIdx.x >> 6);
  int lane = threadIdx.x & 63;
  const float* xr = x + (size_t)t * DMODEL;
  float acc[8];
#pragma unroll
  for (int e = 0; e < 8; e++) acc[e] = 0.f;
#pragma unroll
  for (int j = 0; j < 16; j++){
    int d = lane + 64 * j;
    float xv = xr[d];
    const f32x4* w = (const f32x4*)(Wr + (size_t)d * 8);
    f32x4 w0 = w[0], w1 = w[1];
    acc[0] += xv * w0.x; acc[1] += xv * w0.y; acc[2] += xv * w0.z; acc[3] += xv * w0.w;
    acc[4] += xv * w1.x; acc[5] += xv * w1.y; acc[6] += xv * w1.z; acc[7] += xv * w1.w;
  }
#pragma unroll
  for (int e = 0; e < 8; e++){
    float v = acc[e];
#pragma unroll
    for (int o = 32; o > 0; o >>= 1) v += __shfl_xor(v, o, 64);
    acc[e] = v;
  }
  if (lane == 0){
    float lg[8];
#pragma unroll
    for (int e = 0; e < 8; e++) lg[e] = acc[e] + br[e];
    int i0 = 0; float v0 = lg[0];
#pragma unroll
    for (int e = 1; e < 8; e++) if (lg[e] > v0){ v0 = lg[e]; i0 = e; }   // first max (tie: lowest idx)
    int i1 = -1; float v1 = -3.4e38f;
#pragma unroll
    for (int e = 0; e < 8; e++) if (e != i0 && lg[e] > v1){ v1 = lg[e]; i1 = e; }
    float ew = __expf(v1 - v0);               // <= 1
    float w1 = ew / (1.f + ew);
    float w0 = 1.f - w1;
    int s0 = atomicAdd(&cnt[i0], 1);
    int s1 = atomicAdd(&cnt[i1], 1);
    list[i0 * TCAP + s0] = t;
    list[i1 * TCAP + s1] = t;
    tk_e[2*t]   = i0; tk_s[2*t]   = s0; tk_g[2*t]   = w0;
    tk_e[2*t+1] = i1; tk_s[2*t+1] = s1; tk_g[2*t+1] = w1;
  }
}

__global__ void scan_kernel(const int* __restrict__ cnt, int* __restrict__ off){
  if (threadIdx.x == 0 && blockIdx.x == 0){
    int o = 0;
    for (int e = 0; e < NEXP; e++){ off[e] = o; o += cnt[e]; }
    off[NEXP] = o;
  }
}

// ---------------- x fp32 -> bf16 ----------------
__global__ __launch_bounds__(256) void xconv_kernel(const float* __restrict__ x,
                                                    unsigned short* __restrict__ xb)
{
  size_t i = (size_t)(blockIdx.x * 256 + threadIdx.x) * 8;
  f32x4 a = *(const f32x4*)(x + i);
  f32x4 b = *(const f32x4*)(x + i + 4);
  short8 o;
  o[0]=(short)f2bf(a.x); o[1]=(short)f2bf(a.y); o[2]=(short)f2bf(a.z); o[3]=(short)f2bf(a.w);
  o[4]=(short)f2bf(b.x); o[5]=(short)f2bf(b.y); o[6]=(short)f2bf(b.z); o[7]=(short)f2bf(b.w);
  *(short8*)(xb + i) = o;
}

// ---------------- weight transpose + fp32->bf16:  src[E][R][C] -> dst[E][C][R] ----------------
__global__ __launch_bounds__(256) void transpose_kernel(const float* __restrict__ src,
                                                        unsigned short* __restrict__ dst,
                                                        int R, int C)
{
  __shared__ float tile[32][33];
  int e = blockIdx.z;
  size_t ebase = (size_t)e * R * C;
  int c0 = blockIdx.x * 32;
  int r0 = blockIdx.y * 32;
  int tx = threadIdx.x & 31;
  int ty = threadIdx.x >> 5;      // 0..7
  const float* s = src + ebase;
  unsigned short* d = dst + ebase;
#pragma unroll
  for (int i = 0; i < 4; i++)
    tile[ty + 8*i][tx] = s[(size_t)(r0 + ty + 8*i) * C + c0 + tx];
  __syncthreads();
#pragma unroll
  for (int i = 0; i < 4; i++)
    d[(size_t)(c0 + ty + 8*i) * R + r0 + tx] = f2bf(tile[tx][ty + 8*i]);
}

// ---------------- grouped GEMM (B pre-transposed bf16) ----------------
// 256x128 tile, BK=64, 512 threads (8 waves as 4Mx2N, per-wave 64x64 output).
// 3-buffer LDS, prefetch distance 2, counted vmcnt(6) (T4), asm ds_read_b128
// (opaque to compiler -> no auto vmcnt(0) serialization), T2 XOR swizzle
// (pre-swizzled global source + swizzled read, rule #21), T5 setprio.
// MODE 0: h = gelu(A@B^T + b1) -> bf16 ;  MODE 1: y (+)= A@B^T -> fp32
template<int MODE>
__global__ __launch_bounds__(512, 1) void gemm_kernel(
    const unsigned short* __restrict__ A0, int lda,
    const int* __restrict__ list,                    // null => rows are off[e]+r
    const unsigned short* __restrict__ B0, int ldb, long strideBe,
    const int* __restrict__ cnt, const int* __restrict__ off,
    int K,
    unsigned short* __restrict__ hout, float* __restrict__ yout, int ldout,
    const float* __restrict__ bias, int nbase, int accum)
{
  int e = blockIdx.z;
  int cnte = cnt[e];
  int bm = blockIdx.y;
  if (bm * 256 >= cnte) return;
  int bn = blockIdx.x;
  int offe = off[e];

  // 3 buffers x (A 32KB + B 16KB) = 144KB
  __shared__ unsigned short smem[3][(256 + 128) * 64];

  int tid  = threadIdx.x;
  int lane = tid & 63;
  int wav  = tid >> 6;        // 0..7
  // T2: source slot pre-swizzled so LINEAR LDS dest holds swizzled data.
  // stage row&7 == (tid>>3)&7 for both A (c*64 + tid>>3) and B.
  int sslot = (tid & 7) ^ ((tid >> 3) & 7);

  // staging source pointers: A = 4 x async16/thread, B = 2 x async16/thread per k-step
  const unsigned short* aptr[4];
  const unsigned short* bptr[2];
  const unsigned short* Be = B0 + (size_t)e * strideBe;
#pragma unroll
  for (int c = 0; c < 4; c++){
    int r  = bm * 256 + c * 64 + (tid >> 3);        // global tile row
    int rr = min(r, cnte - 1);
    long arow = list ? (long)list[(size_t)e * TCAP + rr] : (long)(offe + rr);
    aptr[c] = A0 + (size_t)arow * lda + sslot * 8;
  }
#pragma unroll
  for (int c = 0; c < 2; c++){
    int n = bn * 128 + c * 64 + (tid >> 3);
    bptr[c] = Be + (size_t)n * ldb + sslot * 8;
  }

  auto stage = [&](int buf, int k0){
    char* Ad = (char*)smem + (size_t)buf * 49152;
    char* Bd = Ad + 32768;
#pragma unroll
    for (int c = 0; c < 4; c++)
      async16(Ad + c * 8192 + wav * 1024, aptr[c] + k0);
#pragma unroll
    for (int c = 0; c < 2; c++)
      async16(Bd + c * 8192 + wav * 1024, bptr[c] + k0);
  };

  f32x4 acc[4][4] = {};

  int wm = wav >> 1, wn = wav & 1;
  int l15 = lane & 15, l4 = lane >> 4;
  int swz = lane & 7;          // == row&7 == col&7 of the fragment rows this lane reads

  int NT = K >> 6;
  stage(0, 0);
  stage(1, 64);
  int cur = 0;
  for (int t = 0; t < NT; t++){
    // my tile-t loads are the oldest 6 of <=12 outstanding
    if (t < NT - 1) asm volatile("s_waitcnt vmcnt(6)" ::: "memory");
    else            asm volatile("s_waitcnt vmcnt(0)" ::: "memory");
    __builtin_amdgcn_s_barrier();                    // all waves: tile t landed; step t-1 reads done
    __builtin_amdgcn_sched_barrier(0);
    if (t + 2 < NT) stage((cur + 2) % 3, (t + 2) << 6);   // overwrites buf read at t-1: safe
    char* Ab = (char*)smem + (size_t)cur * 49152;
    char* Bb = Ab + 32768;
#pragma unroll
    for (int kk = 0; kk < 2; kk++){
      short8 a[4], b[4];
      int k8 = kk * 4 + l4;
      int ks = (k8 ^ swz) << 4;                      // T2 swizzled 16B slot
#pragma unroll
      for (int m = 0; m < 4; m++){
        int row = wm * 64 + m * 16 + l15;
        a[m] = lds_read_b128(Ab + row * 128 + ks);
      }
#pragma unroll
      for (int n = 0; n < 4; n++){
        int col = wn * 64 + n * 16 + l15;
        b[n] = lds_read_b128(Bb + col * 128 + ks);
      }
      asm volatile("s_waitcnt lgkmcnt(0)" ::: "memory");
      __builtin_amdgcn_sched_barrier(0);             // rule #18: pin MFMAs after the wait
      __builtin_amdgcn_s_setprio(1);
#pragma unroll
      for (int m = 0; m < 4; m++)
#pragma unroll
        for (int n = 0; n < 4; n++)
          acc[m][n] = __builtin_amdgcn_mfma_f32_16x16x32_bf16(a[m], b[n], acc[m][n], 0, 0, 0);
      __builtin_amdgcn_s_setprio(0);
    }
    cur = (cur + 1) % 3;
  }

  // epilogue: C/D layout col=lane&15, row=(lane>>4)*4+q  [verified m89/m91]
#pragma unroll
  for (int m = 0; m < 4; m++){
#pragma unroll
    for (int n = 0; n < 4; n++){
      int coll = bn * 128 + wn * 64 + n * 16 + l15;
#pragma unroll
      for (int q = 0; q < 4; q++){
        int r = bm * 256 + wm * 64 + m * 16 + l4 * 4 + q;
        if (r < cnte){
          float v = acc[m][n][q];
          size_t orow = (size_t)(offe + r);
          if (MODE == 0){
            v += bias[(size_t)e * DFF + nbase + coll];
            v = gelu_tanh(v);
            hout[orow * (size_t)ldout + coll] = f2bf(v);
          } else {
            size_t oi = orow * (size_t)ldout + coll;
            if (accum) v += yout[oi];
            yout[oi] = v;
          }
        }
      }
    }
  }
}

// ---------------- combine: out[t] = sum_k g_k * (y[row_k] + b2[e_k]) ----------------
__global__ __launch_bounds__(256) void combine_kernel(
    const float* __restrict__ y, const float* __restrict__ b2,
    const int* __restrict__ off, const int* __restrict__ tk_e,
    const int* __restrict__ tk_s, const float* __restrict__ tk_g,
    float* __restrict__ out)
{
  int t = blockIdx.x;
  int d = threadIdx.x * 4;
  int e0 = tk_e[2*t],  e1 = tk_e[2*t+1];
  int s0 = tk_s[2*t],  s1 = tk_s[2*t+1];
  float g0 = tk_g[2*t], g1 = tk_g[2*t+1];
  size_t r0 = (size_t)(off[e0] + s0) * DMODEL + d;
  size_t r1 = (size_t)(off[e1] + s1) * DMODEL + d;
  f32x4 v0 = *(const f32x4*)(y + r0);
  f32x4 v1 = *(const f32x4*)(y + r1);
  f32x4 c0 = *(const f32x4*)(b2 + (size_t)e0 * DMODEL + d);
  f32x4 c1 = *(const f32x4*)(b2 + (size_t)e1 * DMODEL + d);
  f32x4 o  = g0 * (v0 + c0) + g1 * (v1 + c1);
  *(f32x4*)(out + (size_t)t * DMODEL + d) = o;
}

extern "C" void kernel_launch(void* const* d_in, const int* in_sizes, int n_in,
                              void* d_out, int out_size, void* d_ws, size_t ws_size,
                              hipStream_t stream)
{
  const float* x  = (const float*)d_in[0];
  const float* Wr = (const float*)d_in[1];
  const float* br = (const float*)d_in[2];
  const float* W1 = (const float*)d_in[3];
  const float* b1 = (const float*)d_in[4];
  const float* W2 = (const float*)d_in[5];
  const float* b2 = (const float*)d_in[6];
  float* out = (float*)d_out;

  char* ws = (char*)d_ws;
  size_t o = 0;
  auto carve = [&](size_t bytes) -> char* {
    char* p = ws + o;
    o += (bytes + 255) & ~(size_t)255;
    return p;
  };
  int* cnt   = (int*)carve(NEXP * 4);
  int* off   = (int*)carve((NEXP + 1) * 4);
  int* list  = (int*)carve((size_t)NEXP * TCAP * 4);
  int* tk_e  = (int*)carve(TOKENS * 2 * 4);
  int* tk_s  = (int*)carve(TOKENS * 2 * 4);
  float* tk_g = (float*)carve(TOKENS * 2 * 4);
  unsigned short* xb  = (unsigned short*)carve((size_t)TOKENS * DMODEL * 2);
  unsigned short* W1t = (unsigned short*)carve((size_t)NEXP * DFF * DMODEL * 2);
  unsigned short* W2t = (unsigned short*)carve((size_t)NEXP * DFF * DMODEL * 2);
  float* y = (float*)carve((size_t)ROWS * DMODEL * 4);
  size_t used_base = o;

  int nchunk = 0;
  for (int nc = 1; nc <= 8; nc <<= 1){
    size_t need = used_base + (size_t)ROWS * (DFF / nc) * 2 + 256;
    if (need <= ws_size){ nchunk = nc; break; }
  }
  if (!nchunk){
    fprintf(stderr, "kernel_launch: ws too small (%zu bytes, need >= %zu)\n",
            ws_size, used_base + (size_t)ROWS * (DFF / 8) * 2 + 256);
    return;
  }
  int dffc = DFF / nchunk;
  unsigned short* h = (unsigned short*)carve((size_t)ROWS * dffc * 2);

  hipMemsetAsync(cnt, 0, NEXP * 4, stream);
  router_kernel<<<TOKENS / 4, 256, 0, stream>>>(x, Wr, br, cnt, list, tk_e, tk_s, tk_g);
  scan_kernel<<<1, 64, 0, stream>>>(cnt, off);
  xconv_kernel<<<(TOKENS * DMODEL / 8) / 256, 256, 0, stream>>>(x, xb);
  // W1 [E][D][DFF] -> W1t [E][DFF][D]
  transpose_kernel<<<dim3(DFF / 32, DMODEL / 32, NEXP), 256, 0, stream>>>(W1, W1t, DMODEL, DFF);
  // W2 [E][DFF][D] -> W2t [E][D][DFF]
  transpose_kernel<<<dim3(DMODEL / 32, DFF / 32, NEXP), 256, 0, stream>>>(W2, W2t, DFF, DMODEL);

  for (int c = 0; c < nchunk; c++){
    // GEMM1: h[:, 0:dffc] = gelu(x[list] @ W1t(slice)^T + b1(slice))
    gemm_kernel<0><<<dim3(dffc / 128, 16, NEXP), 512, 0, stream>>>(
        xb, DMODEL, list,
        W1t + (size_t)c * dffc * DMODEL, DMODEL, (long)DFF * DMODEL,
        cnt, off, DMODEL,
        h, nullptr, dffc,
        b1, c * dffc, 0);
    // GEMM2: y (+)= h @ W2t(slice)^T
    gemm_kernel<1><<<dim3(DMODEL / 128, 16, NEXP), 512, 0, stream>>>(
        h, dffc, nullptr,
        W2t + (size_t)c * dffc, DFF, (long)DFF * DMODEL,
        cnt, off, dffc,
        nullptr, y, DMODEL,
        nullptr, 0, c > 0);
  }
  combine_kernel<<<TOKENS, 256, 0, stream>>>(y, b2, off, tk_e, tk_s, tk_g, out);
}